// Round 2
// baseline (1218.578 us; speedup 1.0000x reference)
//
#include <hip/hip_runtime.h>

typedef __bf16 bf16;
typedef __bf16 bf16x8 __attribute__((ext_vector_type(8)));
typedef __bf16 bf16x2 __attribute__((ext_vector_type(2)));
typedef float  f32x4  __attribute__((ext_vector_type(4)));

static_assert(sizeof(bf16x8) == 16, "bf16x8 must be 16B");

#define MFMA16(a, b, c) __builtin_amdgcn_mfma_f32_16x16x32_bf16((a), (b), (c), 0, 0, 0)

__device__ __forceinline__ void gload_lds16(const void* g, void* l) {
    __builtin_amdgcn_global_load_lds(
        (const __attribute__((address_space(1))) void*)(uintptr_t)g,
        (__attribute__((address_space(3))) void*)(uintptr_t)l,
        16, 0, 0);
}

// ---------------------------------------------------------------------------
// f32 -> bf16 cast, 8 elements/thread.
// ---------------------------------------------------------------------------
__global__ __launch_bounds__(256)
void cast_f32_bf16(const float* __restrict__ in, bf16* __restrict__ out, int n8)
{
    const int i = blockIdx.x * 256 + threadIdx.x;
    if (i >= n8) return;
    const float4 a = ((const float4*)in)[i * 2];
    const float4 b = ((const float4*)in)[i * 2 + 1];
    bf16x8 o;
    o[0] = (bf16)a.x; o[1] = (bf16)a.y; o[2] = (bf16)a.z; o[3] = (bf16)a.w;
    o[4] = (bf16)b.x; o[5] = (bf16)b.y; o[6] = (bf16)b.z; o[7] = (bf16)b.w;
    ((bf16x8*)out)[i] = o;
}

// ---------------------------------------------------------------------------
// GEMM: C[M,N] = A[M,K] * W[N,K]^T, bf16 in, f32 accumulate, OT out.
// tile 128x128, BK=32, block 256 (4 waves 2x2, each 64x64). m97 structure.
// ---------------------------------------------------------------------------
template <typename OT>
__global__ __launch_bounds__(256)
void gemm_bt(const bf16* __restrict__ A, const bf16* __restrict__ W,
             int K, int ldc, OT* __restrict__ C)
{
    __shared__ bf16 As[128 * 32];
    __shared__ bf16 Bs[128 * 32];

    const int n0 = blockIdx.x * 128;
    const int m0 = blockIdx.y * 128;

    const int tid  = threadIdx.x;
    const int lane = tid & 63;
    const int wid  = tid >> 6;
    const int wm   = wid >> 1;
    const int wn   = wid & 1;
    const int quad = lane >> 4;
    const int l16  = lane & 15;

    // staging: lane l of wave wid -> row wid*32 + (l>>2) (+16 on 2nd issue), col (l&3)*8
    const int srow = wid * 32 + (lane >> 2);
    const int scol = (lane & 3) * 8;
    const bf16* ag = A + (size_t)(m0 + srow) * K + scol;
    const bf16* wg = W + (size_t)(n0 + srow) * K + scol;
    bf16* al = As + wid * 1024;
    bf16* bl = Bs + wid * 1024;

    const bf16* afr = As + (wm * 64 + l16) * 32 + quad * 8;
    const bf16* bfr = Bs + (wn * 64 + l16) * 32 + quad * 8;

    f32x4 acc[4][4];
#pragma unroll
    for (int i = 0; i < 4; i++)
#pragma unroll
        for (int j = 0; j < 4; j++) acc[i][j] = f32x4{0.f, 0.f, 0.f, 0.f};

    for (int kt = 0; kt < K; kt += 32) {
        __syncthreads();
        gload_lds16(ag,          al);
        gload_lds16(ag + 16 * K, al + 512);
        gload_lds16(wg,          bl);
        gload_lds16(wg + 16 * K, bl + 512);
        ag += 32; wg += 32;
        __syncthreads();

        bf16x8 af[4], bfv[4];
#pragma unroll
        for (int i = 0; i < 4; i++) af[i]  = *(const bf16x8*)(afr + i * 16 * 32);
#pragma unroll
        for (int i = 0; i < 4; i++) bfv[i] = *(const bf16x8*)(bfr + i * 16 * 32);
#pragma unroll
        for (int mi = 0; mi < 4; mi++)
#pragma unroll
            for (int ni = 0; ni < 4; ni++)
                acc[mi][ni] = MFMA16(af[mi], bfv[ni], acc[mi][ni]);
    }

#pragma unroll
    for (int mi = 0; mi < 4; mi++) {
        const int row = m0 + wm * 64 + mi * 16 + quad * 4;
#pragma unroll
        for (int ni = 0; ni < 4; ni++) {
            const int col = n0 + wn * 64 + ni * 16 + l16;
#pragma unroll
            for (int r = 0; r < 4; r++)
                C[(size_t)(row + r) * ldc + col] = (OT)acc[mi][ni][r];
        }
    }
}

// ---------------------------------------------------------------------------
// Fused per-head RMSNorm (over 128) + RoPE, in place on q (16 heads) and
// k (4 heads) inside qkv [8192, 3072] (bf16). fc/norm weights are f32.
// One wave per (token, head).
// ---------------------------------------------------------------------------
__global__ __launch_bounds__(256)
void normrope(bf16* __restrict__ qkv, const float* __restrict__ fc,
              const float* __restrict__ qw, const float* __restrict__ kw)
{
    const int row  = blockIdx.x * 4 + (threadIdx.x >> 6);
    const int lane = threadIdx.x & 63;
    const int slot = row % 20;
    const int tok  = row / 20;       // b*4096 + s
    const int s    = tok & 4095;

    const float* w; int off;
    if (slot < 16) { off = slot * 128;               w = qw; }
    else           { off = 2048 + (slot - 16) * 128; w = kw; }

    bf16* p = qkv + (size_t)tok * 3072 + off;

    bf16x2 v = *(const bf16x2*)(p + 2 * lane);
    float x0 = (float)v[0], x1 = (float)v[1];

    float ss = x0 * x0 + x1 * x1;
    ss += __shfl_xor(ss, 1);  ss += __shfl_xor(ss, 2);  ss += __shfl_xor(ss, 4);
    ss += __shfl_xor(ss, 8);  ss += __shfl_xor(ss, 16); ss += __shfl_xor(ss, 32);
    const float r = rsqrtf(ss * (1.0f / 128.0f) + 1e-6f);

    const float xn0 = x0 * r * w[2 * lane], xn1 = x1 * r * w[2 * lane + 1];

    const float2 cs = ((const float2*)fc)[(size_t)s * 64 + lane];
    const float c = cs.x, sn = cs.y;

    bf16x2 o;
    o[0] = (bf16)(xn0 * c - xn1 * sn);
    o[1] = (bf16)(xn0 * sn + xn1 * c);
    *(bf16x2*)(p + 2 * lane) = o;
}

// ---------------------------------------------------------------------------
// V transpose: v[b,s,kvh,d] (strided in qkv) -> vT[b,kvh,d,s]
// ---------------------------------------------------------------------------
__global__ __launch_bounds__(256)
void transpose_v(const bf16* __restrict__ qkv, bf16* __restrict__ vT)
{
    const int idx = blockIdx.x;          // (b*4+kvh)*128 + d
    const int d   = idx & 127;
    const int bk  = idx >> 7;
    const int b   = bk >> 2;
    const int kvh = bk & 3;
    const bf16* src = qkv + (size_t)b * 4096 * 3072 + 2560 + kvh * 128 + d;
    bf16* dst = vT + (size_t)idx * 4096;
    for (int s = threadIdx.x; s < 4096; s += 256)
        dst[s] = src[(size_t)s * 3072];
}

// ---------------------------------------------------------------------------
// Causal flash attention, GQA 4:1. Q-tile 128 (4 waves x 32 rows), KV-tile 64.
// ---------------------------------------------------------------------------
__global__ __launch_bounds__(256)
void flash(const bf16* __restrict__ qkv, const bf16* __restrict__ vT,
           bf16* __restrict__ out)
{
    const int qt  = gridDim.x - 1 - blockIdx.x;   // big tiles first
    const int bh  = blockIdx.y;
    const int b   = bh >> 4, h = bh & 15;
    const int kvh = h >> 2;
    const int q0  = qt * 128;

    const int tid  = threadIdx.x;
    const int lane = tid & 63;
    const int wid  = tid >> 6;
    const int quad = lane >> 4;
    const int l16  = lane & 15;

    __shared__ bf16 Ks[64 * 136];    // stride 136 elems = 272 B (16B-aligned)
    __shared__ bf16 Vs[128 * 88];    // V^T tile: [d][s], stride 88
    __shared__ bf16 Ps[128 * 88];    // per-wave P regions

    bf16x8 qf[2][4];
    const bf16* qbase = qkv + ((size_t)(b * 4096 + q0 + wid * 32)) * 3072 + h * 128;
#pragma unroll
    for (int mt = 0; mt < 2; mt++)
#pragma unroll
        for (int ks = 0; ks < 4; ks++)
            qf[mt][ks] = *(const bf16x8*)(qbase + (size_t)(mt * 16 + l16) * 3072 + ks * 32 + quad * 8);

    f32x4 oacc[2][8];
#pragma unroll
    for (int mt = 0; mt < 2; mt++)
#pragma unroll
        for (int nd = 0; nd < 8; nd++) oacc[mt][nd] = f32x4{0.f, 0.f, 0.f, 0.f};
    float mrow[2][4], lrow[2][4];
#pragma unroll
    for (int mt = 0; mt < 2; mt++)
#pragma unroll
        for (int r = 0; r < 4; r++) { mrow[mt][r] = -__builtin_inff(); lrow[mt][r] = 0.f; }

    const bf16* kbase = qkv + (size_t)b * 4096 * 3072 + 2048 + kvh * 128;
    const bf16* vbase = vT + ((size_t)(b * 4 + kvh) * 128) * 4096;
    const float scale = 0.08838834764831845f;

    const int ntiles = qt * 2 + 2;
    for (int t = 0; t < ntiles; t++) {
        const int kv0 = t * 64;
        __syncthreads();
#pragma unroll
        for (int v2 = 0; v2 < 4; v2++) {
            const int r = v2 * 16 + (tid >> 4);
            const int c = (tid & 15) * 8;
            *(bf16x8*)(Ks + r * 136 + c) = *(const bf16x8*)(kbase + (size_t)(kv0 + r) * 3072 + c);
        }
#pragma unroll
        for (int v2 = 0; v2 < 4; v2++) {
            const int r = v2 * 32 + (tid >> 3);
            const int c = (tid & 7) * 8;
            *(bf16x8*)(Vs + r * 88 + c) = *(const bf16x8*)(vbase + (size_t)r * 4096 + kv0 + c);
        }
        __syncthreads();

        // S = Q K^T
        f32x4 sacc[2][4];
#pragma unroll
        for (int mt = 0; mt < 2; mt++)
#pragma unroll
            for (int nt = 0; nt < 4; nt++) sacc[mt][nt] = f32x4{0.f, 0.f, 0.f, 0.f};
#pragma unroll
        for (int ks = 0; ks < 4; ks++) {
            bf16x8 kf[4];
#pragma unroll
            for (int nt = 0; nt < 4; nt++)
                kf[nt] = *(const bf16x8*)(Ks + (nt * 16 + l16) * 136 + ks * 32 + quad * 8);
#pragma unroll
            for (int mt = 0; mt < 2; mt++)
#pragma unroll
                for (int nt = 0; nt < 4; nt++)
                    sacc[mt][nt] = MFMA16(qf[mt][ks], kf[nt], sacc[mt][nt]);
        }

#pragma unroll
        for (int mt = 0; mt < 2; mt++)
#pragma unroll
            for (int nt = 0; nt < 4; nt++)
#pragma unroll
                for (int r = 0; r < 4; r++) sacc[mt][nt][r] *= scale;

        if (kv0 + 63 > q0) {   // diagonal tiles: causal mask
#pragma unroll
            for (int mt = 0; mt < 2; mt++)
#pragma unroll
                for (int nt = 0; nt < 4; nt++)
#pragma unroll
                    for (int r = 0; r < 4; r++) {
                        const int rg = q0 + wid * 32 + mt * 16 + quad * 4 + r;
                        const int cg = kv0 + nt * 16 + l16;
                        if (cg > rg) sacc[mt][nt][r] = -1e30f;
                    }
        }

        // online softmax; P -> LDS (per-wave region)
        float alpha[2][4];
        bf16* pw = Ps + (size_t)(wid * 32) * 88;
#pragma unroll
        for (int mt = 0; mt < 2; mt++) {
#pragma unroll
            for (int r = 0; r < 4; r++) {
                float mx = fmaxf(fmaxf(sacc[mt][0][r], sacc[mt][1][r]),
                                 fmaxf(sacc[mt][2][r], sacc[mt][3][r]));
                mx = fmaxf(mx, __shfl_xor(mx, 1));
                mx = fmaxf(mx, __shfl_xor(mx, 2));
                mx = fmaxf(mx, __shfl_xor(mx, 4));
                mx = fmaxf(mx, __shfl_xor(mx, 8));
                const float mnew = fmaxf(mrow[mt][r], mx);
                alpha[mt][r] = __expf(mrow[mt][r] - mnew);
                mrow[mt][r] = mnew;
                float rs = 0.f;
#pragma unroll
                for (int nt = 0; nt < 4; nt++) {
                    const float p = __expf(sacc[mt][nt][r] - mnew);
                    rs += p;
                    pw[(mt * 16 + quad * 4 + r) * 88 + nt * 16 + l16] = (bf16)p;
                }
                rs += __shfl_xor(rs, 1); rs += __shfl_xor(rs, 2);
                rs += __shfl_xor(rs, 4); rs += __shfl_xor(rs, 8);
                lrow[mt][r] = lrow[mt][r] * alpha[mt][r] + rs;
            }
        }

#pragma unroll
        for (int mt = 0; mt < 2; mt++)
#pragma unroll
            for (int nd = 0; nd < 8; nd++)
#pragma unroll
                for (int r = 0; r < 4; r++) oacc[mt][nd][r] *= alpha[mt][r];

        // O += P V
#pragma unroll
        for (int ks = 0; ks < 2; ks++) {
            bf16x8 pf[2];
#pragma unroll
            for (int mt = 0; mt < 2; mt++)
                pf[mt] = *(const bf16x8*)(Ps + (size_t)(wid * 32 + mt * 16 + l16) * 88 + ks * 32 + quad * 8);
#pragma unroll
            for (int nd = 0; nd < 8; nd++) {
                const bf16x8 vf = *(const bf16x8*)(Vs + (size_t)(nd * 16 + l16) * 88 + ks * 32 + quad * 8);
#pragma unroll
                for (int mt = 0; mt < 2; mt++)
                    oacc[mt][nd] = MFMA16(pf[mt], vf, oacc[mt][nd]);
            }
        }
    }

#pragma unroll
    for (int mt = 0; mt < 2; mt++) {
#pragma unroll
        for (int r = 0; r < 4; r++) {
            const float inv = 1.0f / lrow[mt][r];
            const size_t srow = (size_t)(b * 4096 + q0 + wid * 32 + mt * 16 + quad * 4 + r);
#pragma unroll
            for (int nd = 0; nd < 8; nd++)
                out[srow * 2048 + h * 128 + nd * 16 + l16] = (bf16)(oacc[mt][nd][r] * inv);
        }
    }
}

// ---------------------------------------------------------------------------
extern "C" void kernel_launch(void* const* d_in, const int* in_sizes, int n_in,
                              void* d_out, int out_size, void* d_ws, size_t ws_size,
                              hipStream_t stream)
{
    const float* x   = (const float*)d_in[0];
    const float* fc  = (const float*)d_in[1];
    const float* wq  = (const float*)d_in[2];
    const float* wk  = (const float*)d_in[3];
    const float* wv  = (const float*)d_in[4];
    const float* wo  = (const float*)d_in[5];
    const float* qnw = (const float*)d_in[6];
    const float* knw = (const float*)d_in[7];
    float* out = (float*)d_out;

    // workspace layout (100 MB total, with aliasing):
    //   [0,        50331648)  qkv bf16 [8192,3072]
    //   [50331648, 58720256)  vT  bf16 [2,4,128,4096]
    //   [58720256, 92274688)  xb (x as bf16) during gemm1, then att (flash out)
    //   [92274688, 104857600) wqkv bf16 [3072,2048] during gemm1, then wo bf16
    char* ws = (char*)d_ws;
    bf16* qkv = (bf16*)ws;
    bf16* vT  = (bf16*)(ws + 50331648);
    bf16* xb  = (bf16*)(ws + 58720256);
    bf16* att = xb;
    bf16* wb  = (bf16*)(ws + 92274688);
    bf16* wob = wb;

    // 0) casts: x -> bf16, [wq;wk;wv] -> bf16 (contiguous rows)
    cast_f32_bf16<<<dim3(8192), 256, 0, stream>>>(x, xb, 2097152);
    cast_f32_bf16<<<dim3(2048), 256, 0, stream>>>(wq, wb, 524288);
    cast_f32_bf16<<<dim3(512),  256, 0, stream>>>(wk, wb + 2048 * 2048, 131072);
    cast_f32_bf16<<<dim3(512),  256, 0, stream>>>(wv, wb + 2560 * 2048, 131072);
    // 1) fused QKV projection: qkv[8192,3072] = xb @ wb^T
    gemm_bt<bf16><<<dim3(24, 64), 256, 0, stream>>>(xb, wb, 2048, 3072, qkv);
    // 2) RMSNorm + RoPE on q,k heads in place
    normrope<<<dim3(40960), 256, 0, stream>>>(qkv, fc, qnw, knw);
    // 3) V -> V^T
    transpose_v<<<dim3(1024), 256, 0, stream>>>(qkv, vT);
    // 4) causal flash attention (writes att, aliasing xb - xb is dead now)
    flash<<<dim3(32, 32), 256, 0, stream>>>(qkv, vT, att);
    // 5) wo -> bf16 (aliases wqkv region - dead after gemm1)
    cast_f32_bf16<<<dim3(2048), 256, 0, stream>>>(wo, wob, 524288);
    // 6) output projection: out = att @ wob^T (f32 out)
    gemm_bt<float><<<dim3(16, 64), 256, 0, stream>>>(att, wob, 2048, 2048, out);
}

// Round 3
// 1100.245 us; speedup vs baseline: 1.1076x; 1.1076x over previous
//
#include <hip/hip_runtime.h>

typedef __bf16 bf16;
typedef __bf16 bf16x8 __attribute__((ext_vector_type(8)));
typedef __bf16 bf16x2 __attribute__((ext_vector_type(2)));
typedef float  f32x4  __attribute__((ext_vector_type(4)));

static_assert(sizeof(bf16x8) == 16, "bf16x8 must be 16B");

#define MFMA16(a, b, c) __builtin_amdgcn_mfma_f32_16x16x32_bf16((a), (b), (c), 0, 0, 0)

__device__ __forceinline__ void gload_lds16(const void* g, void* l) {
    __builtin_amdgcn_global_load_lds(
        (const __attribute__((address_space(1))) void*)(uintptr_t)g,
        (__attribute__((address_space(3))) void*)(uintptr_t)l,
        16, 0, 0);
}

// ---------------------------------------------------------------------------
// f32 -> bf16 cast, 8 elements/thread.
// ---------------------------------------------------------------------------
__global__ __launch_bounds__(256)
void cast_f32_bf16(const float* __restrict__ in, bf16* __restrict__ out, int n8)
{
    const int i = blockIdx.x * 256 + threadIdx.x;
    if (i >= n8) return;
    const float4 a = ((const float4*)in)[i * 2];
    const float4 b = ((const float4*)in)[i * 2 + 1];
    bf16x8 o;
    o[0] = (bf16)a.x; o[1] = (bf16)a.y; o[2] = (bf16)a.z; o[3] = (bf16)a.w;
    o[4] = (bf16)b.x; o[5] = (bf16)b.y; o[6] = (bf16)b.z; o[7] = (bf16)b.w;
    ((bf16x8*)out)[i] = o;
}

// ---------------------------------------------------------------------------
// GEMM: C[M,N] = A[M,K] * W[N,K]^T, bf16 in, f32 accumulate, OT out.
// tile 128x128, BK=32, block 256 (4 waves 2x2, each 64x64). m97 structure.
// ---------------------------------------------------------------------------
template <typename OT>
__global__ __launch_bounds__(256)
void gemm_bt(const bf16* __restrict__ A, const bf16* __restrict__ W,
             int K, int ldc, OT* __restrict__ C)
{
    __shared__ bf16 As[128 * 32];
    __shared__ bf16 Bs[128 * 32];

    const int n0 = blockIdx.x * 128;
    const int m0 = blockIdx.y * 128;

    const int tid  = threadIdx.x;
    const int lane = tid & 63;
    const int wid  = tid >> 6;
    const int wm   = wid >> 1;
    const int wn   = wid & 1;
    const int quad = lane >> 4;
    const int l16  = lane & 15;

    const int srow = wid * 32 + (lane >> 2);
    const int scol = (lane & 3) * 8;
    const bf16* ag = A + (size_t)(m0 + srow) * K + scol;
    const bf16* wg = W + (size_t)(n0 + srow) * K + scol;
    bf16* al = As + wid * 1024;
    bf16* bl = Bs + wid * 1024;

    const bf16* afr = As + (wm * 64 + l16) * 32 + quad * 8;
    const bf16* bfr = Bs + (wn * 64 + l16) * 32 + quad * 8;

    f32x4 acc[4][4];
#pragma unroll
    for (int i = 0; i < 4; i++)
#pragma unroll
        for (int j = 0; j < 4; j++) acc[i][j] = f32x4{0.f, 0.f, 0.f, 0.f};

    for (int kt = 0; kt < K; kt += 32) {
        __syncthreads();
        gload_lds16(ag,          al);
        gload_lds16(ag + 16 * K, al + 512);
        gload_lds16(wg,          bl);
        gload_lds16(wg + 16 * K, bl + 512);
        ag += 32; wg += 32;
        __syncthreads();

        bf16x8 af[4], bfv[4];
#pragma unroll
        for (int i = 0; i < 4; i++) af[i]  = *(const bf16x8*)(afr + i * 16 * 32);
#pragma unroll
        for (int i = 0; i < 4; i++) bfv[i] = *(const bf16x8*)(bfr + i * 16 * 32);
#pragma unroll
        for (int mi = 0; mi < 4; mi++)
#pragma unroll
            for (int ni = 0; ni < 4; ni++)
                acc[mi][ni] = MFMA16(af[mi], bfv[ni], acc[mi][ni]);
    }

#pragma unroll
    for (int mi = 0; mi < 4; mi++) {
        const int row = m0 + wm * 64 + mi * 16 + quad * 4;
#pragma unroll
        for (int ni = 0; ni < 4; ni++) {
            const int col = n0 + wn * 64 + ni * 16 + l16;
#pragma unroll
            for (int r = 0; r < 4; r++)
                C[(size_t)(row + r) * ldc + col] = (OT)acc[mi][ni][r];
        }
    }
}

// ---------------------------------------------------------------------------
// Fused per-head RMSNorm (over 128) + RoPE, in place on q (16 heads) and
// k (4 heads) inside qkv [8192, 3072] (bf16). fc/norm weights are f32.
// Q heads additionally scaled by (1/sqrt(128))*log2(e) so attention logits
// come out of QK^T already in the exp2 domain.
// ---------------------------------------------------------------------------
__global__ __launch_bounds__(256)
void normrope(bf16* __restrict__ qkv, const float* __restrict__ fc,
              const float* __restrict__ qw, const float* __restrict__ kw)
{
    const int row  = blockIdx.x * 4 + (threadIdx.x >> 6);
    const int lane = threadIdx.x & 63;
    const int slot = row % 20;
    const int tok  = row / 20;       // b*4096 + s
    const int s    = tok & 4095;

    const float* w; int off; float post;
    if (slot < 16) { off = slot * 128;               w = qw; post = 0.12751681555f; }
    else           { off = 2048 + (slot - 16) * 128; w = kw; post = 1.0f; }

    bf16* p = qkv + (size_t)tok * 3072 + off;

    bf16x2 v = *(const bf16x2*)(p + 2 * lane);
    float x0 = (float)v[0], x1 = (float)v[1];

    float ss = x0 * x0 + x1 * x1;
    ss += __shfl_xor(ss, 1);  ss += __shfl_xor(ss, 2);  ss += __shfl_xor(ss, 4);
    ss += __shfl_xor(ss, 8);  ss += __shfl_xor(ss, 16); ss += __shfl_xor(ss, 32);
    const float r = rsqrtf(ss * (1.0f / 128.0f) + 1e-6f) * post;

    const float xn0 = x0 * r * w[2 * lane], xn1 = x1 * r * w[2 * lane + 1];

    const float2 cs = ((const float2*)fc)[(size_t)s * 64 + lane];
    const float c = cs.x, sn = cs.y;

    bf16x2 o;
    o[0] = (bf16)(xn0 * c - xn1 * sn);
    o[1] = (bf16)(xn0 * sn + xn1 * c);
    *(bf16x2*)(p + 2 * lane) = o;
}

// ---------------------------------------------------------------------------
// V transpose: v[b,s,kvh,d] (strided in qkv) -> vT[b,kvh,d,s]
// ---------------------------------------------------------------------------
__global__ __launch_bounds__(256)
void transpose_v(const bf16* __restrict__ qkv, bf16* __restrict__ vT)
{
    const int idx = blockIdx.x;          // (b*4+kvh)*128 + d
    const int d   = idx & 127;
    const int bk  = idx >> 7;
    const int b   = bk >> 2;
    const int kvh = bk & 3;
    const bf16* src = qkv + (size_t)b * 4096 * 3072 + 2560 + kvh * 128 + d;
    bf16* dst = vT + (size_t)idx * 4096;
    for (int s = threadIdx.x; s < 4096; s += 256)
        dst[s] = src[(size_t)s * 3072];
}

// ---------------------------------------------------------------------------
// Causal flash attention, GQA 4:1. Q-tile 128 (4 waves x 32 rows), KV-tile 64.
// Each block processes the q-tile PAIR (bx, 31-bx): uniform 66 kv-tile units
// per block, 512 blocks = exactly 2 resident/CU on 256 CUs (LDS-capped).
// Logits arrive pre-scaled to the exp2 domain (see normrope).
// ---------------------------------------------------------------------------
__global__ __launch_bounds__(256)
void flash(const bf16* __restrict__ qkv, const bf16* __restrict__ vT,
           bf16* __restrict__ out)
{
    const int bh  = blockIdx.y;
    const int b   = bh >> 4, h = bh & 15;
    const int kvh = h >> 2;

    const int tid  = threadIdx.x;
    const int lane = tid & 63;
    const int wid  = tid >> 6;
    const int quad = lane >> 4;
    const int l16  = lane & 15;

    __shared__ bf16 Ks[64 * 136];    // stride 136 elems = 272 B (16B-aligned)
    __shared__ bf16 Vs[128 * 88];    // V^T tile: [d][s], stride 88
    __shared__ bf16 Ps[128 * 88];    // per-wave P regions

    const bf16* kbase = qkv + (size_t)b * 4096 * 3072 + 2048 + kvh * 128;
    const bf16* vbase = vT + ((size_t)(b * 4 + kvh) * 128) * 4096;

    for (int pass = 0; pass < 2; ++pass) {
        const int qt = pass ? (31 - blockIdx.x) : blockIdx.x;
        const int q0 = qt * 128;

        // Q fragments (A-layout), 2 m-tiles x 4 k-steps
        bf16x8 qf[2][4];
        const bf16* qbase = qkv + ((size_t)(b * 4096 + q0 + wid * 32)) * 3072 + h * 128;
#pragma unroll
        for (int mt = 0; mt < 2; mt++)
#pragma unroll
            for (int ks = 0; ks < 4; ks++)
                qf[mt][ks] = *(const bf16x8*)(qbase + (size_t)(mt * 16 + l16) * 3072 + ks * 32 + quad * 8);

        f32x4 oacc[2][8];
#pragma unroll
        for (int mt = 0; mt < 2; mt++)
#pragma unroll
            for (int nd = 0; nd < 8; nd++) oacc[mt][nd] = f32x4{0.f, 0.f, 0.f, 0.f};
        float mrow[2][4], lrow[2][4];
#pragma unroll
        for (int mt = 0; mt < 2; mt++)
#pragma unroll
            for (int r = 0; r < 4; r++) { mrow[mt][r] = -__builtin_inff(); lrow[mt][r] = 0.f; }

        const int ntiles = qt * 2 + 2;
        for (int t = 0; t < ntiles; t++) {
            const int kv0 = t * 64;
            __syncthreads();
#pragma unroll
            for (int v2 = 0; v2 < 4; v2++) {
                const int r = v2 * 16 + (tid >> 4);
                const int c = (tid & 15) * 8;
                *(bf16x8*)(Ks + r * 136 + c) = *(const bf16x8*)(kbase + (size_t)(kv0 + r) * 3072 + c);
            }
#pragma unroll
            for (int v2 = 0; v2 < 4; v2++) {
                const int r = v2 * 32 + (tid >> 3);
                const int c = (tid & 7) * 8;
                *(bf16x8*)(Vs + r * 88 + c) = *(const bf16x8*)(vbase + (size_t)r * 4096 + kv0 + c);
            }
            __syncthreads();

            // S = Q K^T (logits already in exp2 domain)
            f32x4 sacc[2][4];
#pragma unroll
            for (int mt = 0; mt < 2; mt++)
#pragma unroll
                for (int nt = 0; nt < 4; nt++) sacc[mt][nt] = f32x4{0.f, 0.f, 0.f, 0.f};
#pragma unroll
            for (int ks = 0; ks < 4; ks++) {
                bf16x8 kf[4];
#pragma unroll
                for (int nt = 0; nt < 4; nt++)
                    kf[nt] = *(const bf16x8*)(Ks + (nt * 16 + l16) * 136 + ks * 32 + quad * 8);
#pragma unroll
                for (int mt = 0; mt < 2; mt++)
#pragma unroll
                    for (int nt = 0; nt < 4; nt++)
                        sacc[mt][nt] = MFMA16(qf[mt][ks], kf[nt], sacc[mt][nt]);
            }

            if (kv0 + 63 > q0) {   // diagonal tiles: causal mask
#pragma unroll
                for (int mt = 0; mt < 2; mt++)
#pragma unroll
                    for (int nt = 0; nt < 4; nt++)
#pragma unroll
                        for (int r = 0; r < 4; r++) {
                            const int rg = q0 + wid * 32 + mt * 16 + quad * 4 + r;
                            const int cg = kv0 + nt * 16 + l16;
                            if (cg > rg) sacc[mt][nt][r] = -1e30f;
                        }
            }

            // ---- online softmax, ILP-restructured ----
            // partial max per row (in-lane over nt)
            float pm[2][4];
#pragma unroll
            for (int mt = 0; mt < 2; mt++)
#pragma unroll
                for (int r = 0; r < 4; r++)
                    pm[mt][r] = fmaxf(fmaxf(sacc[mt][0][r], sacc[mt][1][r]),
                                      fmaxf(sacc[mt][2][r], sacc[mt][3][r]));
            // 4 xor-rounds, 8 parallel chains
#pragma unroll
            for (int d = 1; d <= 8; d <<= 1)
#pragma unroll
                for (int mt = 0; mt < 2; mt++)
#pragma unroll
                    for (int r = 0; r < 4; r++)
                        pm[mt][r] = fmaxf(pm[mt][r], __shfl_xor(pm[mt][r], d));

            float alpha[2][4], ps[2][4];
#pragma unroll
            for (int mt = 0; mt < 2; mt++)
#pragma unroll
                for (int r = 0; r < 4; r++) {
                    const float mnew = fmaxf(mrow[mt][r], pm[mt][r]);
                    alpha[mt][r] = exp2f(mrow[mt][r] - mnew);
                    mrow[mt][r] = mnew;
                    ps[mt][r] = 0.f;
                }

            // exps + P store (independent, 32-way ILP)
            bf16* pw = Ps + (size_t)(wid * 32) * 88;
#pragma unroll
            for (int mt = 0; mt < 2; mt++)
#pragma unroll
                for (int nt = 0; nt < 4; nt++)
#pragma unroll
                    for (int r = 0; r < 4; r++) {
                        const float p = exp2f(sacc[mt][nt][r] - mrow[mt][r]);
                        ps[mt][r] += p;
                        pw[(mt * 16 + quad * 4 + r) * 88 + nt * 16 + l16] = (bf16)p;
                    }
            // 4 xor-rounds for sums, 8 parallel chains
#pragma unroll
            for (int d = 1; d <= 8; d <<= 1)
#pragma unroll
                for (int mt = 0; mt < 2; mt++)
#pragma unroll
                    for (int r = 0; r < 4; r++)
                        ps[mt][r] += __shfl_xor(ps[mt][r], d);
#pragma unroll
            for (int mt = 0; mt < 2; mt++)
#pragma unroll
                for (int r = 0; r < 4; r++)
                    lrow[mt][r] = lrow[mt][r] * alpha[mt][r] + ps[mt][r];

            // rescale O
#pragma unroll
            for (int mt = 0; mt < 2; mt++)
#pragma unroll
                for (int nd = 0; nd < 8; nd++)
#pragma unroll
                    for (int r = 0; r < 4; r++) oacc[mt][nd][r] *= alpha[mt][r];

            // O += P V
#pragma unroll
            for (int ks = 0; ks < 2; ks++) {
                bf16x8 pf[2];
#pragma unroll
                for (int mt = 0; mt < 2; mt++)
                    pf[mt] = *(const bf16x8*)(Ps + (size_t)(wid * 32 + mt * 16 + l16) * 88 + ks * 32 + quad * 8);
#pragma unroll
                for (int nd = 0; nd < 8; nd++) {
                    const bf16x8 vf = *(const bf16x8*)(Vs + (size_t)(nd * 16 + l16) * 88 + ks * 32 + quad * 8);
#pragma unroll
                    for (int mt = 0; mt < 2; mt++)
                        oacc[mt][nd] = MFMA16(pf[mt], vf, oacc[mt][nd]);
                }
            }
        }

        // epilogue: O / l -> out[b, s, h*128 + d]
#pragma unroll
        for (int mt = 0; mt < 2; mt++) {
#pragma unroll
            for (int r = 0; r < 4; r++) {
                const float inv = 1.0f / lrow[mt][r];
                const size_t srow = (size_t)(b * 4096 + q0 + wid * 32 + mt * 16 + quad * 4 + r);
#pragma unroll
                for (int nd = 0; nd < 8; nd++)
                    out[srow * 2048 + h * 128 + nd * 16 + l16] = (bf16)(oacc[mt][nd][r] * inv);
            }
        }
    }
}

// ---------------------------------------------------------------------------
extern "C" void kernel_launch(void* const* d_in, const int* in_sizes, int n_in,
                              void* d_out, int out_size, void* d_ws, size_t ws_size,
                              hipStream_t stream)
{
    const float* x   = (const float*)d_in[0];
    const float* fc  = (const float*)d_in[1];
    const float* wq  = (const float*)d_in[2];
    const float* wk  = (const float*)d_in[3];
    const float* wv  = (const float*)d_in[4];
    const float* wo  = (const float*)d_in[5];
    const float* qnw = (const float*)d_in[6];
    const float* knw = (const float*)d_in[7];
    float* out = (float*)d_out;

    // workspace layout (100 MB total, with aliasing):
    //   [0,        50331648)  qkv bf16 [8192,3072]
    //   [50331648, 58720256)  vT  bf16 [2,4,128,4096]
    //   [58720256, 92274688)  xb (x as bf16) during gemm1, then att (flash out)
    //   [92274688, 104857600) wqkv bf16 [3072,2048] during gemm1, then wo bf16
    char* ws = (char*)d_ws;
    bf16* qkv = (bf16*)ws;
    bf16* vT  = (bf16*)(ws + 50331648);
    bf16* xb  = (bf16*)(ws + 58720256);
    bf16* att = xb;
    bf16* wb  = (bf16*)(ws + 92274688);
    bf16* wob = wb;

    // 0) casts: x -> bf16, [wq;wk;wv] -> bf16 (contiguous rows)
    cast_f32_bf16<<<dim3(8192), 256, 0, stream>>>(x, xb, 2097152);
    cast_f32_bf16<<<dim3(2048), 256, 0, stream>>>(wq, wb, 524288);
    cast_f32_bf16<<<dim3(512),  256, 0, stream>>>(wk, wb + 2048 * 2048, 131072);
    cast_f32_bf16<<<dim3(512),  256, 0, stream>>>(wv, wb + 2560 * 2048, 131072);
    // 1) fused QKV projection: qkv[8192,3072] = xb @ wb^T
    gemm_bt<bf16><<<dim3(24, 64), 256, 0, stream>>>(xb, wb, 2048, 3072, qkv);
    // 2) RMSNorm + RoPE on q,k heads in place (q pre-scaled for exp2 softmax)
    normrope<<<dim3(40960), 256, 0, stream>>>(qkv, fc, qnw, knw);
    // 3) V -> V^T
    transpose_v<<<dim3(1024), 256, 0, stream>>>(qkv, vT);
    // 4) causal flash attention, load-balanced q-tile pairs
    flash<<<dim3(16, 32), 256, 0, stream>>>(qkv, vT, att);
    // 5) wo -> bf16 (aliases wqkv region - dead after gemm1)
    cast_f32_bf16<<<dim3(2048), 256, 0, stream>>>(wo, wob, 524288);
    // 6) output projection: out = att @ wob^T (f32 out)
    gemm_bt<float><<<dim3(16, 64), 256, 0, stream>>>(att, wob, 2048, 2048, out);
}

// Round 4
// 858.133 us; speedup vs baseline: 1.4200x; 1.2821x over previous
//
#include <hip/hip_runtime.h>

typedef __bf16 bf16;
typedef __bf16 bf16x8 __attribute__((ext_vector_type(8)));
typedef __bf16 bf16x2 __attribute__((ext_vector_type(2)));
typedef float  f32x4  __attribute__((ext_vector_type(4)));

static_assert(sizeof(bf16x8) == 16, "bf16x8 must be 16B");

#define MFMA16(a, b, c) __builtin_amdgcn_mfma_f32_16x16x32_bf16((a), (b), (c), 0, 0, 0)

__device__ __forceinline__ void gload_lds16(const void* g, void* l) {
    __builtin_amdgcn_global_load_lds(
        (const __attribute__((address_space(1))) void*)(uintptr_t)g,
        (__attribute__((address_space(3))) void*)(uintptr_t)l,
        16, 0, 0);
}

// ---------------------------------------------------------------------------
// f32 -> bf16 cast, 8 elements/thread.
// ---------------------------------------------------------------------------
__global__ __launch_bounds__(256)
void cast_f32_bf16(const float* __restrict__ in, bf16* __restrict__ out, int n8)
{
    const int i = blockIdx.x * 256 + threadIdx.x;
    if (i >= n8) return;
    const float4 a = ((const float4*)in)[i * 2];
    const float4 b = ((const float4*)in)[i * 2 + 1];
    bf16x8 o;
    o[0] = (bf16)a.x; o[1] = (bf16)a.y; o[2] = (bf16)a.z; o[3] = (bf16)a.w;
    o[4] = (bf16)b.x; o[5] = (bf16)b.y; o[6] = (bf16)b.z; o[7] = (bf16)b.w;
    ((bf16x8*)out)[i] = o;
}

// ---------------------------------------------------------------------------
// GEMM: C[M,N] = A[M,K] * W[N,K]^T, bf16 in, f32 accumulate, OT out.
// tile 128x128, BK=32, block 256 (4 waves 2x2, each 64x64). m97 structure.
// ---------------------------------------------------------------------------
template <typename OT>
__global__ __launch_bounds__(256)
void gemm_bt(const bf16* __restrict__ A, const bf16* __restrict__ W,
             int K, int ldc, OT* __restrict__ C)
{
    __shared__ bf16 As[128 * 32];
    __shared__ bf16 Bs[128 * 32];

    const int n0 = blockIdx.x * 128;
    const int m0 = blockIdx.y * 128;

    const int tid  = threadIdx.x;
    const int lane = tid & 63;
    const int wid  = tid >> 6;
    const int wm   = wid >> 1;
    const int wn   = wid & 1;
    const int quad = lane >> 4;
    const int l16  = lane & 15;

    const int srow = wid * 32 + (lane >> 2);
    const int scol = (lane & 3) * 8;
    const bf16* ag = A + (size_t)(m0 + srow) * K + scol;
    const bf16* wg = W + (size_t)(n0 + srow) * K + scol;
    bf16* al = As + wid * 1024;
    bf16* bl = Bs + wid * 1024;

    const bf16* afr = As + (wm * 64 + l16) * 32 + quad * 8;
    const bf16* bfr = Bs + (wn * 64 + l16) * 32 + quad * 8;

    f32x4 acc[4][4];
#pragma unroll
    for (int i = 0; i < 4; i++)
#pragma unroll
        for (int j = 0; j < 4; j++) acc[i][j] = f32x4{0.f, 0.f, 0.f, 0.f};

    for (int kt = 0; kt < K; kt += 32) {
        __syncthreads();
        gload_lds16(ag,          al);
        gload_lds16(ag + 16 * K, al + 512);
        gload_lds16(wg,          bl);
        gload_lds16(wg + 16 * K, bl + 512);
        ag += 32; wg += 32;
        __syncthreads();

        bf16x8 af[4], bfv[4];
#pragma unroll
        for (int i = 0; i < 4; i++) af[i]  = *(const bf16x8*)(afr + i * 16 * 32);
#pragma unroll
        for (int i = 0; i < 4; i++) bfv[i] = *(const bf16x8*)(bfr + i * 16 * 32);
#pragma unroll
        for (int mi = 0; mi < 4; mi++)
#pragma unroll
            for (int ni = 0; ni < 4; ni++)
                acc[mi][ni] = MFMA16(af[mi], bfv[ni], acc[mi][ni]);
    }

#pragma unroll
    for (int mi = 0; mi < 4; mi++) {
        const int row = m0 + wm * 64 + mi * 16 + quad * 4;
#pragma unroll
        for (int ni = 0; ni < 4; ni++) {
            const int col = n0 + wn * 64 + ni * 16 + l16;
#pragma unroll
            for (int r = 0; r < 4; r++)
                C[(size_t)(row + r) * ldc + col] = (OT)acc[mi][ni][r];
        }
    }
}

// ---------------------------------------------------------------------------
// Fused per-head RMSNorm (over 128) + RoPE, in place on q (16 heads) and
// k (4 heads) inside qkv [8192, 3072] (bf16). fc/norm weights are f32.
// Q heads additionally scaled by (1/sqrt(128))*log2(e) for exp2-domain softmax.
// ---------------------------------------------------------------------------
__global__ __launch_bounds__(256)
void normrope(bf16* __restrict__ qkv, const float* __restrict__ fc,
              const float* __restrict__ qw, const float* __restrict__ kw)
{
    const int row  = blockIdx.x * 4 + (threadIdx.x >> 6);
    const int lane = threadIdx.x & 63;
    const int slot = row % 20;
    const int tok  = row / 20;       // b*4096 + s
    const int s    = tok & 4095;

    const float* w; int off; float post;
    if (slot < 16) { off = slot * 128;               w = qw; post = 0.12751681555f; }
    else           { off = 2048 + (slot - 16) * 128; w = kw; post = 1.0f; }

    bf16* p = qkv + (size_t)tok * 3072 + off;

    bf16x2 v = *(const bf16x2*)(p + 2 * lane);
    float x0 = (float)v[0], x1 = (float)v[1];

    float ss = x0 * x0 + x1 * x1;
    ss += __shfl_xor(ss, 1);  ss += __shfl_xor(ss, 2);  ss += __shfl_xor(ss, 4);
    ss += __shfl_xor(ss, 8);  ss += __shfl_xor(ss, 16); ss += __shfl_xor(ss, 32);
    const float r = rsqrtf(ss * (1.0f / 128.0f) + 1e-6f) * post;

    const float xn0 = x0 * r * w[2 * lane], xn1 = x1 * r * w[2 * lane + 1];

    const float2 cs = ((const float2*)fc)[(size_t)s * 64 + lane];
    const float c = cs.x, sn = cs.y;

    bf16x2 o;
    o[0] = (bf16)(xn0 * c - xn1 * sn);
    o[1] = (bf16)(xn0 * sn + xn1 * c);
    *(bf16x2*)(p + 2 * lane) = o;
}

// ---------------------------------------------------------------------------
// V transpose: v[b,s,kvh,d] (strided in qkv) -> vT[b,kvh,d,s]
// ---------------------------------------------------------------------------
__global__ __launch_bounds__(256)
void transpose_v(const bf16* __restrict__ qkv, bf16* __restrict__ vT)
{
    const int idx = blockIdx.x;          // (b*4+kvh)*128 + d
    const int d   = idx & 127;
    const int bk  = idx >> 7;
    const int b   = bk >> 2;
    const int kvh = bk & 3;
    const bf16* src = qkv + (size_t)b * 4096 * 3072 + 2560 + kvh * 128 + d;
    bf16* dst = vT + (size_t)idx * 4096;
    for (int s = threadIdx.x; s < 4096; s += 256)
        dst[s] = src[(size_t)s * 3072];
}

// ---------------------------------------------------------------------------
// Causal flash attention, GQA 4:1. Q-tile 128 (4 waves x 32 rows), KV-tile 64.
// Block processes q-tile pair (bx, 31-bx): uniform 66 units/block, 512 blocks.
// Software-pipelined: K double-buffered, K[t+1] and V[t] issued via async
// global_load_lds right after the top barrier, draining at the mid barrier
// (overlapped with QK+softmax). LDS layouts are unpadded with XOR-8 granule
// swizzle (LDS[row][g] holds global granule g^(row&7)) -> 2-way reads (free),
// contiguous conflict-free staging writes. Total LDS 64 KB -> 2 blocks/CU.
// ---------------------------------------------------------------------------
__global__ __launch_bounds__(256)
void flash(const bf16* __restrict__ qkv, const bf16* __restrict__ vT,
           bf16* __restrict__ out)
{
    const int bh  = blockIdx.y;
    const int b   = bh >> 4, h = bh & 15;
    const int kvh = h >> 2;

    const int tid  = threadIdx.x;
    const int lane = tid & 63;
    const int wid  = tid >> 6;
    const int quad = lane >> 4;
    const int l16  = lane & 15;
    const int key  = l16 & 7;        // read-side swizzle key (row&7 == l16&7 everywhere)

    __shared__ bf16 Ks[2][64 * 128]; // [kv][d], 16 granules/row, swizzled
    __shared__ bf16 Vs[128 * 64];    // [d][kv], 8 granules/row, swizzled
    __shared__ bf16 Ps[128 * 64];    // [q][kv], 8 granules/row, swizzled

    const bf16* kbase = qkv + (size_t)b * 4096 * 3072 + 2048 + kvh * 128;
    const bf16* vbase = vT + ((size_t)(b * 4 + kvh) * 128) * 4096;

    // staging lane decomposition
    const int krow_off = lane >> 4;            // 0..3   (4 rows / 1KB instr)
    const int kcolg    = lane & 15;            // 16B granule within 256B K row
    const int vrow_off = lane >> 3;            // 0..7   (8 rows / 1KB instr)
    const int vcolg    = lane & 7;             // granule within 128B V row

    for (int pass = 0; pass < 2; ++pass) {
        const int qt = pass ? (31 - blockIdx.x) : blockIdx.x;
        const int q0 = qt * 128;
        const int ntiles = qt * 2 + 2;

        __syncthreads();   // buffers free from previous pass
        // preload K tile 0 -> Ks[0]
#pragma unroll
        for (int i = 0; i < 4; i++) {
            const int r0 = wid * 16 + i * 4;
            const int rk = r0 + krow_off;
            const int gc = (kcolg ^ (rk & 7)) * 8;
            gload_lds16(kbase + (size_t)rk * 3072 + gc, &Ks[0][r0 * 128]);
        }

        // Q fragments (A-layout), 2 m-tiles x 4 k-steps (overlaps preload)
        bf16x8 qf[2][4];
        const bf16* qbase = qkv + ((size_t)(b * 4096 + q0 + wid * 32)) * 3072 + h * 128;
#pragma unroll
        for (int mt = 0; mt < 2; mt++)
#pragma unroll
            for (int ks = 0; ks < 4; ks++)
                qf[mt][ks] = *(const bf16x8*)(qbase + (size_t)(mt * 16 + l16) * 3072 + ks * 32 + quad * 8);

        f32x4 oacc[2][8];
#pragma unroll
        for (int mt = 0; mt < 2; mt++)
#pragma unroll
            for (int nd = 0; nd < 8; nd++) oacc[mt][nd] = f32x4{0.f, 0.f, 0.f, 0.f};
        float mrow[2][4], lrow[2][4];
#pragma unroll
        for (int mt = 0; mt < 2; mt++)
#pragma unroll
            for (int r = 0; r < 4; r++) { mrow[mt][r] = -__builtin_inff(); lrow[mt][r] = 0.f; }

        int cur = 0;
        for (int t = 0; t < ntiles; t++) {
            const int kv0 = t * 64;
            __syncthreads();   // (A) K[t] landed; Vs/Ps/other-K free

            // issue V[t] -> Vs and K[t+1] -> Ks[1-cur] (async, drain at (E))
#pragma unroll
            for (int i = 0; i < 4; i++) {
                const int r0 = wid * 32 + i * 8;
                const int dv = r0 + vrow_off;
                const int gc = (vcolg ^ (dv & 7)) * 8;
                gload_lds16(vbase + (size_t)dv * 4096 + kv0 + gc, &Vs[r0 * 64]);
            }
            const int kvn = (t + 1 < ntiles) ? kv0 + 64 : kv0;  // clamp last
#pragma unroll
            for (int i = 0; i < 4; i++) {
                const int r0 = wid * 16 + i * 4;
                const int rk = r0 + krow_off;
                const int gc = (kcolg ^ (rk & 7)) * 8;
                gload_lds16(kbase + (size_t)(kvn + rk) * 3072 + gc, &Ks[1 - cur][r0 * 128]);
            }

            // S = Q K^T from Ks[cur] (logits already in exp2 domain)
            f32x4 sacc[2][4];
#pragma unroll
            for (int mt = 0; mt < 2; mt++)
#pragma unroll
                for (int nt = 0; nt < 4; nt++) sacc[mt][nt] = f32x4{0.f, 0.f, 0.f, 0.f};
#pragma unroll
            for (int ks = 0; ks < 4; ks++) {
                bf16x8 kf[4];
#pragma unroll
                for (int nt = 0; nt < 4; nt++)
                    kf[nt] = *(const bf16x8*)(&Ks[cur][(nt * 16 + l16) * 128 + (((ks * 4 + quad) ^ key) * 8)]);
#pragma unroll
                for (int mt = 0; mt < 2; mt++)
#pragma unroll
                    for (int nt = 0; nt < 4; nt++)
                        sacc[mt][nt] = MFMA16(qf[mt][ks], kf[nt], sacc[mt][nt]);
            }

            if (kv0 + 63 > q0) {   // diagonal tiles: causal mask
#pragma unroll
                for (int mt = 0; mt < 2; mt++)
#pragma unroll
                    for (int nt = 0; nt < 4; nt++)
#pragma unroll
                        for (int r = 0; r < 4; r++) {
                            const int rg = q0 + wid * 32 + mt * 16 + quad * 4 + r;
                            const int cg = kv0 + nt * 16 + l16;
                            if (cg > rg) sacc[mt][nt][r] = -1e30f;
                        }
            }

            // ---- online softmax (ILP-restructured) ----
            float pm[2][4];
#pragma unroll
            for (int mt = 0; mt < 2; mt++)
#pragma unroll
                for (int r = 0; r < 4; r++)
                    pm[mt][r] = fmaxf(fmaxf(sacc[mt][0][r], sacc[mt][1][r]),
                                      fmaxf(sacc[mt][2][r], sacc[mt][3][r]));
#pragma unroll
            for (int d = 1; d <= 8; d <<= 1)
#pragma unroll
                for (int mt = 0; mt < 2; mt++)
#pragma unroll
                    for (int r = 0; r < 4; r++)
                        pm[mt][r] = fmaxf(pm[mt][r], __shfl_xor(pm[mt][r], d));

            float alpha[2][4], ps[2][4];
#pragma unroll
            for (int mt = 0; mt < 2; mt++)
#pragma unroll
                for (int r = 0; r < 4; r++) {
                    const float mnew = fmaxf(mrow[mt][r], pm[mt][r]);
                    alpha[mt][r] = exp2f(mrow[mt][r] - mnew);
                    mrow[mt][r] = mnew;
                    ps[mt][r] = 0.f;
                }

            // exps + swizzled P stores (per-wave region, no barrier needed)
#pragma unroll
            for (int mt = 0; mt < 2; mt++)
#pragma unroll
                for (int nt = 0; nt < 4; nt++)
#pragma unroll
                    for (int r = 0; r < 4; r++) {
                        const float p = exp2f(sacc[mt][nt][r] - mrow[mt][r]);
                        ps[mt][r] += p;
                        const int prow = wid * 32 + mt * 16 + quad * 4 + r;
                        const int pg   = (2 * nt + (l16 >> 3)) ^ ((quad * 4 + r) & 7);
                        Ps[prow * 64 + pg * 8 + (l16 & 7)] = (bf16)p;
                    }
#pragma unroll
            for (int d = 1; d <= 8; d <<= 1)
#pragma unroll
                for (int mt = 0; mt < 2; mt++)
#pragma unroll
                    for (int r = 0; r < 4; r++)
                        ps[mt][r] += __shfl_xor(ps[mt][r], d);
#pragma unroll
            for (int mt = 0; mt < 2; mt++)
#pragma unroll
                for (int r = 0; r < 4; r++)
                    lrow[mt][r] = lrow[mt][r] * alpha[mt][r] + ps[mt][r];

            // rescale O
#pragma unroll
            for (int mt = 0; mt < 2; mt++)
#pragma unroll
                for (int nd = 0; nd < 8; nd++)
#pragma unroll
                    for (int r = 0; r < 4; r++) oacc[mt][nd][r] *= alpha[mt][r];

            __syncthreads();   // (E) V[t] (and K[t+1]) landed

            // O += P V
#pragma unroll
            for (int ks = 0; ks < 2; ks++) {
                bf16x8 pf[2];
#pragma unroll
                for (int mt = 0; mt < 2; mt++)
                    pf[mt] = *(const bf16x8*)(&Ps[(wid * 32 + mt * 16 + l16) * 64 + (((ks * 4 + quad) ^ key) * 8)]);
#pragma unroll
                for (int nd = 0; nd < 8; nd++) {
                    const bf16x8 vf = *(const bf16x8*)(&Vs[(nd * 16 + l16) * 64 + (((ks * 4 + quad) ^ key) * 8)]);
#pragma unroll
                    for (int mt = 0; mt < 2; mt++)
                        oacc[mt][nd] = MFMA16(pf[mt], vf, oacc[mt][nd]);
                }
            }
            cur ^= 1;
        }

        // epilogue: O / l -> out[b, s, h*128 + d]
#pragma unroll
        for (int mt = 0; mt < 2; mt++) {
#pragma unroll
            for (int r = 0; r < 4; r++) {
                const float inv = 1.0f / lrow[mt][r];
                const size_t srow = (size_t)(b * 4096 + q0 + wid * 32 + mt * 16 + quad * 4 + r);
#pragma unroll
                for (int nd = 0; nd < 8; nd++)
                    out[srow * 2048 + h * 128 + nd * 16 + l16] = (bf16)(oacc[mt][nd][r] * inv);
            }
        }
    }
}

// ---------------------------------------------------------------------------
extern "C" void kernel_launch(void* const* d_in, const int* in_sizes, int n_in,
                              void* d_out, int out_size, void* d_ws, size_t ws_size,
                              hipStream_t stream)
{
    const float* x   = (const float*)d_in[0];
    const float* fc  = (const float*)d_in[1];
    const float* wq  = (const float*)d_in[2];
    const float* wk  = (const float*)d_in[3];
    const float* wv  = (const float*)d_in[4];
    const float* wo  = (const float*)d_in[5];
    const float* qnw = (const float*)d_in[6];
    const float* knw = (const float*)d_in[7];
    float* out = (float*)d_out;

    // workspace layout (100 MB total, with aliasing):
    //   [0,        50331648)  qkv bf16 [8192,3072]
    //   [50331648, 58720256)  vT  bf16 [2,4,128,4096]
    //   [58720256, 92274688)  xb (x as bf16) during gemm1, then att (flash out)
    //   [92274688, 104857600) wqkv bf16 [3072,2048] during gemm1, then wo bf16
    char* ws = (char*)d_ws;
    bf16* qkv = (bf16*)ws;
    bf16* vT  = (bf16*)(ws + 50331648);
    bf16* xb  = (bf16*)(ws + 58720256);
    bf16* att = xb;
    bf16* wb  = (bf16*)(ws + 92274688);
    bf16* wob = wb;

    // 0) casts: x -> bf16, [wq;wk;wv] -> bf16 (contiguous rows)
    cast_f32_bf16<<<dim3(8192), 256, 0, stream>>>(x, xb, 2097152);
    cast_f32_bf16<<<dim3(2048), 256, 0, stream>>>(wq, wb, 524288);
    cast_f32_bf16<<<dim3(512),  256, 0, stream>>>(wk, wb + 2048 * 2048, 131072);
    cast_f32_bf16<<<dim3(512),  256, 0, stream>>>(wv, wb + 2560 * 2048, 131072);
    // 1) fused QKV projection: qkv[8192,3072] = xb @ wb^T
    gemm_bt<bf16><<<dim3(24, 64), 256, 0, stream>>>(xb, wb, 2048, 3072, qkv);
    // 2) RMSNorm + RoPE on q,k heads in place (q pre-scaled for exp2 softmax)
    normrope<<<dim3(40960), 256, 0, stream>>>(qkv, fc, qnw, knw);
    // 3) V -> V^T
    transpose_v<<<dim3(1024), 256, 0, stream>>>(qkv, vT);
    // 4) causal flash attention, pipelined, load-balanced q-tile pairs
    flash<<<dim3(16, 32), 256, 0, stream>>>(qkv, vT, att);
    // 5) wo -> bf16 (aliases wqkv region - dead after gemm1)
    cast_f32_bf16<<<dim3(2048), 256, 0, stream>>>(wo, wob, 524288);
    // 6) output projection: out = att @ wob^T (f32 out)
    gemm_bt<float><<<dim3(16, 64), 256, 0, stream>>>(att, wob, 2048, 2048, out);
}